// Round 9
// baseline (136.152 us; speedup 1.0000x reference)
//
#include <hip/hip_runtime.h>
#include <math.h>

// SE(3)-Transformer block, MI355X. B=4, N=192, CS=16, CV=4, DIM=28, NB=10.
// Round 8 candidate, resubmitted (round-8 bench failed on GPU acquisition).
// se3_main fused single-pass. att = sqrt(relu(le/z)) factored as
// sign-gated sqrt(|le|)/sqrt(|z|): accumulate accP (weight sqrt(relu(le)))
// and accN (weight sqrt(relu(-le))) in ONE loop that does emb+FC inline,
// k-chunk score, and v-chunk accumulate; select/scale by z at the end.
// Removes 3 barriers + emb/H/le/att LDS roundtrips + one exposed L2 phase.
// precomp is byte-identical to round 7 (attribution).

#define NN 192
#define TSTRIDE 2560   // floats per node in T: 2 fc * 20 q4 * 16 h * 4
#define MAXM 192

constexpr float C1   = 0.17677669529663687f;  // 1/(4*sqrt(2))  (w1 path)
constexpr float C2   = 0.17677669529663687f;  // 1/(4*sqrt(2))  (w2 path)
constexpr float C3   = 0.35355339059327373f;  // 1/(2*sqrt(2))  (w3 path)
constexpr float C4   = 0.20412414523193154f;  // 1/sqrt(24)     (w4 path)
constexpr float CS1f = 0.17677669529663687f;  // score scalar part
constexpr float CS2f = 0.20412414523193154f;  // score vector part
constexpr float RS10 = 0.31622776601683794f;  // 1/sqrt(10)
constexpr float GAIN4 = 1.679f * 0.25f;       // SILU_GAIN / sqrt(16)
constexpr float SQRT3 = 1.7320508075688772f;
constexpr float CEMB = (float)(1.14136 * 7.3890560989306495 * 3.1622776601683795); // 1.14136*e^2*sqrt(10)

// ---------------------------------------------------------------------------
// Kernel A: per-node precompute. W2 staged in LDS (51.2 KB), 256 threads.
//  T element (fc, h, chunk-float q80) stored at fc*1280 + (q80>>2)*64 + h*4 + (q80&3)
//  chunk semantics (per fc,h, 80 floats):
//   [0..15]  T1[o], [16..19] T2[o], [20..31] T3[o*3+x], [32..79] T4[o*3+x]
// ---------------------------------------------------------------------------
__global__ __launch_bounds__(256) void precomp(
  const float* __restrict__ f, const float* __restrict__ wq_s, const float* __restrict__ wq_v,
  const float* __restrict__ w2k, const float* __restrict__ w2v,
  const float* __restrict__ dws, const float* __restrict__ dwv,
  float* __restrict__ T, float* __restrict__ qd, float* __restrict__ validf)
{
  const int node = blockIdx.x;
  const int tid  = threadIdx.x;
  __shared__ float Wsh[12800];          // w2k (6400) then w2v (6400)
  __shared__ float fsh[28];
  __shared__ float qs_sh[16], qv_sh[12];
  __shared__ int vsh;
  if (tid == 0) vsh = 0;
  if (tid < 28) fsh[tid] = f[node*28 + tid];
  {
    float4* d = (float4*)Wsh;
    const float4* s0 = (const float4*)w2k;
    const float4* s1 = (const float4*)w2v;
    for (int q = tid; q < 1600; q += 256) { d[q] = s0[q]; d[1600 + q] = s1[q]; }
  }
  __syncthreads();
  if (tid < 28 && fsh[tid] != 0.f) vsh = 1;   // benign same-value race
  if (tid < 16) {
    float a = 0.f;
    #pragma unroll
    for (int c = 0; c < 16; ++c) a = fmaf(fsh[c], wq_s[c*16 + tid], a);
    qs_sh[tid] = a * 0.25f;
  } else if (tid < 28) {
    int idx = tid - 16, o = idx / 3, x = idx - o*3;
    float a = 0.f;
    #pragma unroll
    for (int c = 0; c < 4; ++c) a = fmaf(fsh[16 + c*3 + x], wq_v[c*4 + o], a);
    qv_sh[idx] = a * 0.5f;
  }
  __syncthreads();
  if (tid < 16) {
    float a = 0.f;
    #pragma unroll
    for (int c = 0; c < 16; ++c) a = fmaf(qs_sh[c], dws[c*16 + tid], a);
    qd[node*28 + tid] = a * CS1f;
  } else if (tid < 28) {
    int idx = tid - 16, d = idx / 3, x = idx - d*3;
    float a = 0.f;
    #pragma unroll
    for (int c = 0; c < 4; ++c) a = fmaf(qv_sh[c*3 + x], dwv[c*4 + d], a);
    qd[node*28 + tid] = a * CS2f;
  }
  if (tid == 0) validf[node] = vsh ? 1.f : 0.f;

  for (int e = tid; e < 2560; e += 256) {
    const int fc = e >= 1280 ? 1 : 0;
    const int r = e - fc*1280;
    const int h = r / 80, q = r - h*80;
    const float* W = Wsh + fc*6400 + h*400;
    float val = 0.f;
    if (q < 16) {                       // T1
      #pragma unroll
      for (int c = 0; c < 16; ++c) val = fmaf(fsh[c], W[c*16 + q], val);
      val *= C1;
    } else if (q < 20) {                // T2
      const int o = q - 16;
      #pragma unroll
      for (int c = 0; c < 16; ++c) val = fmaf(fsh[c], W[256 + c*4 + o], val);
      val *= C2;
    } else if (q < 32) {                // T3
      const int p = q - 20, o = p / 3, x = p - o*3;
      #pragma unroll
      for (int c = 0; c < 4; ++c) val = fmaf(fsh[16 + c*3 + x], W[320 + c*4 + o], val);
      val *= C3;
    } else {                            // T4
      const int p = q - 32, o = p / 3, x = p - o*3;
      #pragma unroll
      for (int c = 0; c < 4; ++c) val = fmaf(fsh[16 + c*3 + x], W[336 + c*16 + o], val);
      val *= C4;
    }
    T[(size_t)node*TSTRIDE + fc*1280 + (q >> 2)*64 + h*4 + (q & 3)] = val;
  }
}

// ---------------------------------------------------------------------------
// Kernel B: one block (256 thr) per (b,i). Compaction, then ONE fused loop
// over (pair,h) items: emb+FC inline, k-chunk -> score (16-lane reduce),
// le immediately, v-chunk -> accP/accN register accumulate. z-select at end.
// ---------------------------------------------------------------------------
__global__ __launch_bounds__(256) void se3_main(
  const float* __restrict__ pos, const float* __restrict__ w1k, const float* __restrict__ w1v,
  const float* __restrict__ T, const float* __restrict__ qd, const float* __restrict__ validf,
  float* __restrict__ out)
{
  const int bi = blockIdx.x;
  const int b = bi / NN, i = bi - b*NN;
  const int tid = threadIdx.x;
  const int lane = tid & 63, wid = tid >> 6;

  __shared__ float qd_sh[28];
  __shared__ float w1_sh[320];                 // k(160) then v(160), pre-scaled
  __shared__ int   s_node[MAXM];
  __shared__ float s_cut[MAXM], s_dist[MAXM];
  __shared__ float s_shx[MAXM], s_shy[MAXM], s_shz[MAXM];
  __shared__ int   cnt_sh;
  __shared__ float opart[4][57];               // [wave][accP 0..27 | accN 28..55 | z 56]

  if (tid < 28) qd_sh[tid] = qd[bi*28 + tid];
  if (tid < 160) {                             // covers all 320 entries
    w1_sh[tid]       = w1k[tid] * RS10;
    w1_sh[160 + tid] = w1v[tid] * RS10;
  }
  if (tid == 0) cnt_sh = 0;
  const float pix = pos[bi*3+0], piy = pos[bi*3+1], piz = pos[bi*3+2];
  const float vali = validf[bi];
  __syncthreads();

  // Phase 1: mask + compaction
  if (tid < NN) {
    const int nj = b*NN + tid;
    const float dx = pos[nj*3+0]-pix, dy = pos[nj*3+1]-piy, dz = pos[nj*3+2]-piz;
    const float dist = sqrtf(fmaf(dx,dx,fmaf(dy,dy,dz*dz)) + 1e-12f);
    if (tid != i && dist < 1.5f && vali != 0.f && validf[nj] != 0.f) {
      const float cut = expf(-1.f / (10.f * (1.f - dist * (1.f/1.5f))));
      if (cut > 0.f) {
        const int s = atomicAdd(&cnt_sh, 1);
        const float sc = SQRT3 / dist;
        s_node[s] = nj; s_cut[s] = cut; s_dist[s] = dist;
        s_shx[s] = dx*sc; s_shy[s] = dy*sc; s_shz[s] = dz*sc;
      }
    }
  }
  __syncthreads();
  const int M = cnt_sh;
  const int MK = M * 16;

  float accP[28], accN[28];
  #pragma unroll
  for (int c = 0; c < 28; ++c) { accP[c] = 0.f; accN[c] = 0.f; }
  float zacc = 0.f;

  // Phase 2: fused per-(pair,h) loop
  for (int idx = tid; idx < MK; idx += 256) {
    const int pr = idx >> 4, h = idx & 15;
    const int node = s_node[pr];
    const float dist = s_dist[pr], cut = s_cut[pr];
    const float sx = s_shx[pr], sy = s_shy[pr], sz = s_shz[pr];

    // radial basis (redundant per 16-lane group; transcendental pipe, cheap)
    float emb[10];
    #pragma unroll
    for (int k = 0; k < 10; ++k) {
      const float dd = (dist - (float)(k+1)*(1.5f/11.f)) * (11.f/1.5f);
      float e = 0.f;
      if (dd > -1.f && dd < 1.f) e = CEMB * expf(-1.f/(1.f+dd) - 1.f/(1.f-dd));
      emb[k] = e;
    }
    float sk = 0.f, sv = 0.f;
    #pragma unroll
    for (int q = 0; q < 10; ++q) {
      sk = fmaf(emb[q], w1_sh[q*16 + h], sk);
      sv = fmaf(emb[q], w1_sh[160 + q*16 + h], sv);
    }
    const float Hk = GAIN4 * sk / (1.f + expf(-sk));
    const float Hv = GAIN4 * sv / (1.f + expf(-sv));

    const float4* __restrict__ bk = (const float4*)(T + (size_t)node*TSTRIDE);
    float cc[80];
    float4* c4 = (float4*)cc;

    // ---- k chunk -> raw score for this h
    #pragma unroll
    for (int q = 0; q < 20; ++q) c4[q] = bk[q*16 + h];
    float s = 0.f;
    #pragma unroll
    for (int o = 0; o < 16; ++o) {
      const float t4 = fmaf(cc[32+3*o], sx, fmaf(cc[33+3*o], sy, cc[34+3*o]*sz));
      s = fmaf(qd_sh[o], cc[o] + t4, s);
    }
    #pragma unroll
    for (int o = 0; o < 4; ++o) {
      const float qvs = fmaf(qd_sh[16+3*o], sx, fmaf(qd_sh[17+3*o], sy, qd_sh[18+3*o]*sz));
      s = fmaf(qvs, cc[16+o], s);
      s = fmaf(qd_sh[16+3*o], cc[20+3*o+0], s);
      s = fmaf(qd_sh[17+3*o], cc[20+3*o+1], s);
      s = fmaf(qd_sh[18+3*o], cc[20+3*o+2], s);
    }
    s *= Hk;
    #pragma unroll
    for (int d = 1; d < 16; d <<= 1) s += __shfl_xor(s, d);   // group sum over h
    const float le = cut * s;                                 // all 16 lanes hold le
    if (h == 0) zacc += le;                                   // one lane per pair
    const float wp = sqrtf(fmaxf(le, 0.f));
    const float wn = sqrtf(fmaxf(-le, 0.f));

    // ---- v chunk -> weighted accumulate
    const float4* __restrict__ bv = bk + 320;                 // +1280 floats
    #pragma unroll
    for (int q = 0; q < 20; ++q) c4[q] = bv[q*16 + h];
    #pragma unroll
    for (int o = 0; o < 16; ++o) {
      const float t4 = fmaf(cc[32+3*o], sx, fmaf(cc[33+3*o], sy, cc[34+3*o]*sz));
      const float v = Hv * (cc[o] + t4);
      accP[o] = fmaf(wp, v, accP[o]);
      accN[o] = fmaf(wn, v, accN[o]);
    }
    #pragma unroll
    for (int o = 0; o < 4; ++o) {
      const float t2 = cc[16+o];
      const float v0 = Hv * fmaf(sx, t2, cc[20+3*o+0]);
      const float v1 = Hv * fmaf(sy, t2, cc[20+3*o+1]);
      const float v2 = Hv * fmaf(sz, t2, cc[20+3*o+2]);
      accP[16+3*o+0] = fmaf(wp, v0, accP[16+3*o+0]);
      accP[16+3*o+1] = fmaf(wp, v1, accP[16+3*o+1]);
      accP[16+3*o+2] = fmaf(wp, v2, accP[16+3*o+2]);
      accN[16+3*o+0] = fmaf(wn, v0, accN[16+3*o+0]);
      accN[16+3*o+1] = fmaf(wn, v1, accN[16+3*o+1]);
      accN[16+3*o+2] = fmaf(wn, v2, accN[16+3*o+2]);
    }
  }

  // Block-wide reduction of accP(28) + accN(28) + z
  #pragma unroll
  for (int c = 0; c < 28; ++c) {
    float wv = accP[c];
    #pragma unroll
    for (int d = 1; d < 64; d <<= 1) wv += __shfl_xor(wv, d);
    if (lane == 0) opart[wid][c] = wv;
    float wn2 = accN[c];
    #pragma unroll
    for (int d = 1; d < 64; d <<= 1) wn2 += __shfl_xor(wn2, d);
    if (lane == 0) opart[wid][28 + c] = wn2;
  }
  {
    float zz = zacc;
    #pragma unroll
    for (int d = 1; d < 64; d <<= 1) zz += __shfl_xor(zz, d);
    if (lane == 0) opart[wid][56] = zz;
  }
  __syncthreads();

  if (tid < 28) {
    const float z = opart[0][56] + opart[1][56] + opart[2][56] + opart[3][56];
    const float aP = opart[0][tid] + opart[1][tid] + opart[2][tid] + opart[3][tid];
    const float aN = opart[0][28+tid] + opart[1][28+tid] + opart[2][28+tid] + opart[3][28+tid];
    float o;
    if (z > 0.f)      o = aP / sqrtf(z);
    else if (z < 0.f) o = aN / sqrtf(-z);
    else              o = aP;          // reference: z==0 -> z:=1 (incl. M==0 -> 0)
    out[bi*28 + tid] = o;
  }
}

extern "C" void kernel_launch(void* const* d_in, const int* in_sizes, int n_in,
                              void* d_out, int out_size, void* d_ws, size_t ws_size,
                              hipStream_t stream) {
  const float* f      = (const float*)d_in[0];
  const float* pos    = (const float*)d_in[1];
  const float* wq_s   = (const float*)d_in[2];
  const float* wq_v   = (const float*)d_in[3];
  const float* fck_w1 = (const float*)d_in[4];
  const float* fck_w2 = (const float*)d_in[5];
  const float* fcv_w1 = (const float*)d_in[6];
  const float* fcv_w2 = (const float*)d_in[7];
  const float* dot_ws = (const float*)d_in[8];
  const float* dot_wv = (const float*)d_in[9];
  float* outp = (float*)d_out;

  const int BN = in_sizes[0] / 28;   // 768 nodes total (B*N)

  float* T   = (float*)d_ws;                      // BN * 2560
  float* qdp = T + (size_t)BN * TSTRIDE;          // BN * 28
  float* vf  = qdp + (size_t)BN * 28;             // BN

  precomp<<<BN, 256, 0, stream>>>(f, wq_s, wq_v, fck_w2, fcv_w2, dot_ws, dot_wv, T, qdp, vf);
  se3_main<<<BN, 256, 0, stream>>>(pos, fck_w1, fcv_w1, T, qdp, vf, outp);
}

// Round 12
// 112.637 us; speedup vs baseline: 1.2088x; 1.2088x over previous
//
#include <hip/hip_runtime.h>
#include <math.h>

// SE(3)-Transformer block, MI355X. B=4, N=192, CS=16, CV=4, DIM=28, NB=10.
// Round 10 candidate, resubmitted (rounds 10-11 benches failed on infra).
// se3_main REVERTED to round-7 measured-good split-phase version (fused
// single-pass regressed 23->56us: VGPR spills + 16x redundant
// transcendentals). precomp: NPB=3 nodes per block share one 51.2KB W2
// LDS staging (grid 768->256) to amortize staging cost 3x.

#define NN 192
#define TSTRIDE 2560   // floats per node in T: 2 fc * 20 q4 * 16 h * 4
#define MAXM 192
#define NPB 3          // nodes per precomp block

constexpr float C1   = 0.17677669529663687f;  // 1/(4*sqrt(2))  (w1 path)
constexpr float C2   = 0.17677669529663687f;  // 1/(4*sqrt(2))  (w2 path)
constexpr float C3   = 0.35355339059327373f;  // 1/(2*sqrt(2))  (w3 path)
constexpr float C4   = 0.20412414523193154f;  // 1/sqrt(24)     (w4 path)
constexpr float CS1f = 0.17677669529663687f;  // score scalar part
constexpr float CS2f = 0.20412414523193154f;  // score vector part
constexpr float RS10 = 0.31622776601683794f;  // 1/sqrt(10)
constexpr float GAIN4 = 1.679f * 0.25f;       // SILU_GAIN / sqrt(16)
constexpr float SQRT3 = 1.7320508075688772f;
constexpr float CEMB = (float)(1.14136 * 7.3890560989306495 * 3.1622776601683795); // 1.14136*e^2*sqrt(10)

// ---------------------------------------------------------------------------
// Kernel A: per-node precompute, NPB nodes per block sharing one W2 staging.
//  T element (fc, h, chunk-float q80) stored at fc*1280 + (q80>>2)*64 + h*4 + (q80&3)
//  chunk semantics (per fc,h, 80 floats):
//   [0..15]  T1[o], [16..19] T2[o], [20..31] T3[o*3+x], [32..79] T4[o*3+x]
// ---------------------------------------------------------------------------
__global__ __launch_bounds__(256) void precomp(
  const float* __restrict__ f, const float* __restrict__ wq_s, const float* __restrict__ wq_v,
  const float* __restrict__ w2k, const float* __restrict__ w2v,
  const float* __restrict__ dws, const float* __restrict__ dwv,
  float* __restrict__ T, float* __restrict__ qd, float* __restrict__ validf, int BN)
{
  const int node0 = blockIdx.x * NPB;
  const int tid   = threadIdx.x;
  __shared__ float Wsh[12800];          // w2k (6400) then w2v (6400)
  __shared__ float fsh[NPB][28];
  __shared__ float qs_sh[NPB][16], qv_sh[NPB][12];
  __shared__ int vsh[NPB];
  if (tid < NPB) vsh[tid] = 0;
  if (tid < NPB*28) {
    const int n = tid / 28, c = tid - n*28;
    fsh[n][c] = (node0 + n < BN) ? f[(node0 + n)*28 + c] : 0.f;
  }
  {
    float4* d = (float4*)Wsh;
    const float4* s0 = (const float4*)w2k;
    const float4* s1 = (const float4*)w2v;
    for (int q = tid; q < 1600; q += 256) { d[q] = s0[q]; d[1600 + q] = s1[q]; }
  }
  __syncthreads();
  if (tid < NPB*28) {
    const int n = tid / 28, c = tid - n*28;
    if (fsh[n][c] != 0.f) vsh[n] = 1;   // benign same-value race
    if (c < 16) {
      float a = 0.f;
      #pragma unroll
      for (int c2 = 0; c2 < 16; ++c2) a = fmaf(fsh[n][c2], wq_s[c2*16 + c], a);
      qs_sh[n][c] = a * 0.25f;
    } else {
      const int idx = c - 16, o = idx / 3, x = idx - o*3;
      float a = 0.f;
      #pragma unroll
      for (int c2 = 0; c2 < 4; ++c2) a = fmaf(fsh[n][16 + c2*3 + x], wq_v[c2*4 + o], a);
      qv_sh[n][idx] = a * 0.5f;
    }
  }
  __syncthreads();
  if (tid < NPB*28) {
    const int n = tid / 28, c = tid - n*28, node = node0 + n;
    if (node < BN) {
      if (c < 16) {
        float a = 0.f;
        #pragma unroll
        for (int c2 = 0; c2 < 16; ++c2) a = fmaf(qs_sh[n][c2], dws[c2*16 + c], a);
        qd[node*28 + c] = a * CS1f;
      } else {
        const int idx = c - 16, d2 = idx / 3, x = idx - d2*3;
        float a = 0.f;
        #pragma unroll
        for (int c2 = 0; c2 < 4; ++c2) a = fmaf(qv_sh[n][c2*3 + x], dwv[c2*4 + d2], a);
        qd[node*28 + c] = a * CS2f;
      }
      if (c == 0) validf[node] = vsh[n] ? 1.f : 0.f;
    }
  }

  for (int e = tid; e < NPB*2560; e += 256) {
    const int n = e / 2560;
    if (node0 + n >= BN) break;          // n nondecreasing in e
    const int rr = e - n*2560;
    const int fc = rr >= 1280 ? 1 : 0;
    const int r = rr - fc*1280;
    const int h = r / 80, q = r - h*80;
    const float* W = Wsh + fc*6400 + h*400;
    const float* fn = fsh[n];
    float val = 0.f;
    if (q < 16) {                       // T1
      #pragma unroll
      for (int c = 0; c < 16; ++c) val = fmaf(fn[c], W[c*16 + q], val);
      val *= C1;
    } else if (q < 20) {                // T2
      const int o = q - 16;
      #pragma unroll
      for (int c = 0; c < 16; ++c) val = fmaf(fn[c], W[256 + c*4 + o], val);
      val *= C2;
    } else if (q < 32) {                // T3
      const int p = q - 20, o = p / 3, x = p - o*3;
      #pragma unroll
      for (int c = 0; c < 4; ++c) val = fmaf(fn[16 + c*3 + x], W[320 + c*4 + o], val);
      val *= C3;
    } else {                            // T4
      const int p = q - 32, o = p / 3, x = p - o*3;
      #pragma unroll
      for (int c = 0; c < 4; ++c) val = fmaf(fn[16 + c*3 + x], W[336 + c*16 + o], val);
      val *= C4;
    }
    T[(size_t)(node0 + n)*TSTRIDE + fc*1280 + (q >> 2)*64 + h*4 + (q & 3)] = val;
  }
}

// ---------------------------------------------------------------------------
// Kernel B: round-7 measured-good version (byte-identical). One block (256
// thr) per (b,i). Compaction, then (pair,h) items spread over all threads.
// 16-lane groups share a pair -> coalesced 256B loads.
// ---------------------------------------------------------------------------
__global__ __launch_bounds__(256) void se3_main(
  const float* __restrict__ pos, const float* __restrict__ w1k, const float* __restrict__ w1v,
  const float* __restrict__ T, const float* __restrict__ qd, const float* __restrict__ validf,
  float* __restrict__ out)
{
  const int bi = blockIdx.x;
  const int b = bi / NN, i = bi - b*NN;
  const int tid = threadIdx.x;
  const int lane = tid & 63, wid = tid >> 6;

  __shared__ float qd_sh[28];
  __shared__ float w1_sh[320];                 // k(160) then v(160), pre-scaled
  __shared__ int   s_node[MAXM];
  __shared__ float s_cut[MAXM], s_dist[MAXM];
  __shared__ float s_shx[MAXM], s_shy[MAXM], s_shz[MAXM];
  __shared__ float emb_sh[MAXM*10];
  __shared__ float Hk_sh[MAXM*16];
  __shared__ float Hv_sh[MAXM*16];
  __shared__ float le_sh[MAXM];
  __shared__ float att_sh[MAXM];
  __shared__ int   cnt_sh;
  __shared__ float red_sh[4];
  __shared__ float opart[4][28];

  if (tid < 28) qd_sh[tid] = qd[bi*28 + tid];
  if (tid < 160) {                             // covers all 320 entries
    w1_sh[tid]       = w1k[tid] * RS10;
    w1_sh[160 + tid] = w1v[tid] * RS10;
  }
  if (tid == 0) cnt_sh = 0;
  const float pix = pos[bi*3+0], piy = pos[bi*3+1], piz = pos[bi*3+2];
  const float vali = validf[bi];
  __syncthreads();

  // Phase 1: mask + compaction
  if (tid < NN) {
    const int nj = b*NN + tid;
    const float dx = pos[nj*3+0]-pix, dy = pos[nj*3+1]-piy, dz = pos[nj*3+2]-piz;
    const float dist = sqrtf(fmaf(dx,dx,fmaf(dy,dy,dz*dz)) + 1e-12f);
    if (tid != i && dist < 1.5f && vali != 0.f && validf[nj] != 0.f) {
      const float cut = expf(-1.f / (10.f * (1.f - dist * (1.f/1.5f))));
      if (cut > 0.f) {
        const int s = atomicAdd(&cnt_sh, 1);
        const float sc = SQRT3 / dist;
        s_node[s] = nj; s_cut[s] = cut; s_dist[s] = dist;
        s_shx[s] = dx*sc; s_shy[s] = dy*sc; s_shz[s] = dz*sc;
      }
    }
  }
  __syncthreads();
  const int M = cnt_sh;
  const int MK = M * 16;

  // Phase 2a: radial basis per (pair, k)
  for (int idx = tid; idx < M*10; idx += 256) {
    const int pr = idx / 10, k = idx - pr*10;
    const float dd = (s_dist[pr] - (float)(k+1)*(1.5f/11.f)) * (11.f/1.5f);
    float e = 0.f;
    if (dd > -1.f && dd < 1.f) e = CEMB * expf(-1.f/(1.f+dd) - 1.f/(1.f-dd));
    emb_sh[idx] = e;
  }
  __syncthreads();

  // Phase 2b: FC hidden per (pair, fc, h)
  for (int idx = tid; idx < M*32; idx += 256) {
    const int pr = idx >> 5, t = idx & 31, h = t & 15;
    const float* w = w1_sh + (t >> 4)*160;
    const float* e = emb_sh + pr*10;
    float s = 0.f;
    #pragma unroll
    for (int q = 0; q < 10; ++q) s = fmaf(e[q], w[q*16 + h], s);
    const float hh = GAIN4 * s / (1.f + expf(-s));
    float* dst = (t < 16) ? Hk_sh : Hv_sh;
    dst[pr*16 + h] = hh;
  }
  __syncthreads();

  // Phase 2c: k-pass -> per-pair raw score in le_sh
  for (int idx = tid; idx < MK; idx += 256) {
    const int pr = idx >> 4, h = idx & 15;
    const int node = s_node[pr];
    const float sx = s_shx[pr], sy = s_shy[pr], sz = s_shz[pr];
    const float a = Hk_sh[idx];
    const float4* b4 = (const float4*)(T + (size_t)node*TSTRIDE);
    float cc[80];
    float4* c4 = (float4*)cc;
    #pragma unroll
    for (int q = 0; q < 20; ++q) c4[q] = b4[q*16 + h];
    float s = 0.f;
    #pragma unroll
    for (int o = 0; o < 16; ++o) {
      const float t4 = fmaf(cc[32+3*o], sx, fmaf(cc[33+3*o], sy, cc[34+3*o]*sz));
      s = fmaf(qd_sh[o], cc[o] + t4, s);
    }
    #pragma unroll
    for (int o = 0; o < 4; ++o) {
      const float qvs = fmaf(qd_sh[16+3*o], sx, fmaf(qd_sh[17+3*o], sy, qd_sh[18+3*o]*sz));
      s = fmaf(qvs, cc[16+o], s);
      s = fmaf(qd_sh[16+3*o], cc[20+3*o+0], s);
      s = fmaf(qd_sh[17+3*o], cc[20+3*o+1], s);
      s = fmaf(qd_sh[18+3*o], cc[20+3*o+2], s);
    }
    s *= a;
    #pragma unroll
    for (int d = 1; d < 16; d <<= 1) s += __shfl_xor(s, d);   // MK multiple of 16 -> uniform per 16-group
    if ((tid & 15) == 0) le_sh[pr] = s;
  }
  __syncthreads();

  // z + att per pair
  float les = 0.f;
  if (tid < M) les = s_cut[tid] * le_sh[tid];
  float z = les;
  #pragma unroll
  for (int d = 1; d < 64; d <<= 1) z += __shfl_xor(z, d);
  if (lane == 0) red_sh[wid] = z;
  __syncthreads();
  z = red_sh[0] + red_sh[1] + red_sh[2] + red_sh[3];
  if (z == 0.f) z = 1.f;
  if (tid < M) {
    const float alpha = les / z;
    att_sh[tid] = alpha > 0.f ? sqrtf(alpha) : 0.f;
  }
  __syncthreads();

  // Phase 3: v-pass with att folded in
  float acc[28];
  #pragma unroll
  for (int c = 0; c < 28; ++c) acc[c] = 0.f;
  for (int idx = tid; idx < MK; idx += 256) {
    const int pr = idx >> 4, h = idx & 15;
    const int node = s_node[pr];
    const float sx = s_shx[pr], sy = s_shy[pr], sz = s_shz[pr];
    const float a = Hv_sh[idx] * att_sh[pr];
    const float4* b4 = (const float4*)(T + (size_t)node*TSTRIDE + 1280);
    float cc[80];
    float4* c4 = (float4*)cc;
    #pragma unroll
    for (int q = 0; q < 20; ++q) c4[q] = b4[q*16 + h];
    #pragma unroll
    for (int o = 0; o < 16; ++o) {
      const float t4 = fmaf(cc[32+3*o], sx, fmaf(cc[33+3*o], sy, cc[34+3*o]*sz));
      acc[o] = fmaf(a, cc[o] + t4, acc[o]);
    }
    const float ax = a*sx, ay = a*sy, az = a*sz;
    #pragma unroll
    for (int o = 0; o < 4; ++o) {
      const float t2 = cc[16+o];
      acc[16+3*o+0] = fmaf(ax, t2, fmaf(a, cc[20+3*o+0], acc[16+3*o+0]));
      acc[16+3*o+1] = fmaf(ay, t2, fmaf(a, cc[20+3*o+1], acc[16+3*o+1]));
      acc[16+3*o+2] = fmaf(az, t2, fmaf(a, cc[20+3*o+2], acc[16+3*o+2]));
    }
  }

  // block-wide 28-element reduction
  #pragma unroll
  for (int c = 0; c < 28; ++c) {
    float w = acc[c];
    #pragma unroll
    for (int d = 1; d < 64; d <<= 1) w += __shfl_xor(w, d);
    if (lane == 0) opart[wid][c] = w;
  }
  __syncthreads();
  if (tid < 28) out[bi*28 + tid] = opart[0][tid] + opart[1][tid] + opart[2][tid] + opart[3][tid];
}

extern "C" void kernel_launch(void* const* d_in, const int* in_sizes, int n_in,
                              void* d_out, int out_size, void* d_ws, size_t ws_size,
                              hipStream_t stream) {
  const float* f      = (const float*)d_in[0];
  const float* pos    = (const float*)d_in[1];
  const float* wq_s   = (const float*)d_in[2];
  const float* wq_v   = (const float*)d_in[3];
  const float* fck_w1 = (const float*)d_in[4];
  const float* fck_w2 = (const float*)d_in[5];
  const float* fcv_w1 = (const float*)d_in[6];
  const float* fcv_w2 = (const float*)d_in[7];
  const float* dot_ws = (const float*)d_in[8];
  const float* dot_wv = (const float*)d_in[9];
  float* outp = (float*)d_out;

  const int BN = in_sizes[0] / 28;   // 768 nodes total (B*N)

  float* T   = (float*)d_ws;                      // BN * 2560
  float* qdp = T + (size_t)BN * TSTRIDE;          // BN * 28
  float* vf  = qdp + (size_t)BN * 28;             // BN

  const int pblocks = (BN + NPB - 1) / NPB;
  precomp<<<pblocks, 256, 0, stream>>>(f, wq_s, wq_v, fck_w2, fcv_w2, dot_ws, dot_wv, T, qdp, vf, BN);
  se3_main<<<BN, 256, 0, stream>>>(pos, fck_w1, fcv_w1, T, qdp, vf, outp);
}

// Round 14
// 105.026 us; speedup vs baseline: 1.2964x; 1.0725x over previous
//
#include <hip/hip_runtime.h>
#include <math.h>

// SE(3)-Transformer block, MI355X. B=4, N=192, CS=16, CV=4, DIM=28, NB=10.
// Round 13 candidate, resubmitted (round-13 bench failed on GPU acquisition).
// precomp re-tiled as 2D grid (node-group x (fc,h) chunk), staging only ONE
// W2 row (1.6KB) + 16 nodes' f (1.8KB) per block instead of the full 51.2KB
// W2 (NPB=3 regression showed amortizing the big stage kills the occupancy
// that hid it; so shrink the stage instead). W2 device traffic 39MB->2.4MB,
// 1536 blocks = 6/CU. qd/valid folded into ch==0 blocks.
// se3_main: byte-identical round-7 measured-good version (~23us).

#define NN 192
#define TSTRIDE 2560   // floats per node in T: 2 fc * 20 q4 * 16 h * 4
#define MAXM 192
#define GN 16          // nodes per precomp block (group)

constexpr float C1   = 0.17677669529663687f;  // 1/(4*sqrt(2))  (w1 path)
constexpr float C2   = 0.17677669529663687f;  // 1/(4*sqrt(2))  (w2 path)
constexpr float C3   = 0.35355339059327373f;  // 1/(2*sqrt(2))  (w3 path)
constexpr float C4   = 0.20412414523193154f;  // 1/sqrt(24)     (w4 path)
constexpr float CS1f = 0.17677669529663687f;  // score scalar part
constexpr float CS2f = 0.20412414523193154f;  // score vector part
constexpr float RS10 = 0.31622776601683794f;  // 1/sqrt(10)
constexpr float GAIN4 = 1.679f * 0.25f;       // SILU_GAIN / sqrt(16)
constexpr float SQRT3 = 1.7320508075688772f;
constexpr float CEMB = (float)(1.14136 * 7.3890560989306495 * 3.1622776601683795); // 1.14136*e^2*sqrt(10)

// ---------------------------------------------------------------------------
// Kernel A: T precompute, one block per (node-group, fc, h).
//  grid.x = NG*32; ng = bid>>5, ch = bid&31, fc = ch>>4, h = ch&15.
//  Stages: Wrow[400] (the single (fc,h) W2 row) + fsh[GN][28].
//  T element (fc, h, q in [0,80)) stored at
//    node*TSTRIDE + fc*1280 + (q>>2)*64 + h*4 + (q&3)   [same layout as r7]
//  ch==0 blocks additionally compute qd + validf for their GN nodes.
// ---------------------------------------------------------------------------
__global__ __launch_bounds__(256) void precomp_T(
  const float* __restrict__ f, const float* __restrict__ wq_s, const float* __restrict__ wq_v,
  const float* __restrict__ w2k, const float* __restrict__ w2v,
  const float* __restrict__ dws, const float* __restrict__ dwv,
  float* __restrict__ T, float* __restrict__ qd, float* __restrict__ validf)
{
  const int bid = blockIdx.x;
  const int ng = bid >> 5, ch = bid & 31;
  const int fc = ch >> 4, h = ch & 15;
  const int node0 = ng * GN;
  const int tid = threadIdx.x;

  __shared__ float Wrow[400];
  __shared__ float fsh[GN][28];
  __shared__ float qs_sh[GN][16], qv_sh[GN][12];
  __shared__ int   vsh[GN];

  {
    const float* Wsrc = (fc ? w2v : w2k) + h*400;
    if (tid < 100) ((float4*)Wrow)[tid] = ((const float4*)Wsrc)[tid];
    else if (tid < 212) ((float4*)fsh)[tid - 100] = ((const float4*)(f + node0*28))[tid - 100];
    if (tid < GN) vsh[tid] = 0;
  }
  __syncthreads();

  // T-build: GN*80 = 1280 outputs, 5 per thread
  #pragma unroll
  for (int k = 0; k < 5; ++k) {
    const int out = tid + k*256;
    const int n = out / 80, q = out - n*80;
    const float* fn = fsh[n];
    float val = 0.f;
    if (q < 16) {                       // T1
      #pragma unroll
      for (int c = 0; c < 16; ++c) val = fmaf(fn[c], Wrow[c*16 + q], val);
      val *= C1;
    } else if (q < 20) {                // T2
      const int o = q - 16;
      #pragma unroll
      for (int c = 0; c < 16; ++c) val = fmaf(fn[c], Wrow[256 + c*4 + o], val);
      val *= C2;
    } else if (q < 32) {                // T3
      const int p = q - 20, o = p / 3, x = p - o*3;
      #pragma unroll
      for (int c = 0; c < 4; ++c) val = fmaf(fn[16 + c*3 + x], Wrow[320 + c*4 + o], val);
      val *= C3;
    } else {                            // T4
      const int p = q - 32, o = p / 3, x = p - o*3;
      #pragma unroll
      for (int c = 0; c < 4; ++c) val = fmaf(fn[16 + c*3 + x], Wrow[336 + c*16 + o], val);
      val *= C4;
    }
    T[(size_t)(node0 + n)*TSTRIDE + fc*1280 + (q >> 2)*64 + h*4 + (q & 3)] = val;
  }

  // qd + validf: only ch==0 blocks (one per node-group)
  if (ch == 0) {
    for (int t = tid; t < GN*28; t += 256) {
      const int n = t / 28, c = t - n*28;
      if (fsh[n][c] != 0.f) vsh[n] = 1;        // benign same-value race
      if (c < 16) {
        float a = 0.f;
        #pragma unroll
        for (int c2 = 0; c2 < 16; ++c2) a = fmaf(fsh[n][c2], wq_s[c2*16 + c], a);
        qs_sh[n][c] = a * 0.25f;
      } else {
        const int idx = c - 16, o = idx / 3, x = idx - o*3;
        float a = 0.f;
        #pragma unroll
        for (int c2 = 0; c2 < 4; ++c2) a = fmaf(fsh[n][16 + c2*3 + x], wq_v[c2*4 + o], a);
        qv_sh[n][idx] = a * 0.5f;
      }
    }
    __syncthreads();
    for (int t = tid; t < GN*28; t += 256) {
      const int n = t / 28, c = t - n*28, node = node0 + n;
      if (c < 16) {
        float a = 0.f;
        #pragma unroll
        for (int c2 = 0; c2 < 16; ++c2) a = fmaf(qs_sh[n][c2], dws[c2*16 + c], a);
        qd[node*28 + c] = a * CS1f;
      } else {
        const int idx = c - 16, d2 = idx / 3, x = idx - d2*3;
        float a = 0.f;
        #pragma unroll
        for (int c2 = 0; c2 < 4; ++c2) a = fmaf(qv_sh[n][c2*3 + x], dwv[c2*4 + d2], a);
        qd[node*28 + c] = a * CS2f;
      }
      if (c == 0) validf[node] = vsh[n] ? 1.f : 0.f;
    }
  }
}

// ---------------------------------------------------------------------------
// Kernel B: round-7 measured-good version (byte-identical). One block (256
// thr) per (b,i). Compaction, then (pair,h) items spread over all threads.
// 16-lane groups share a pair -> coalesced 256B loads.
// ---------------------------------------------------------------------------
__global__ __launch_bounds__(256) void se3_main(
  const float* __restrict__ pos, const float* __restrict__ w1k, const float* __restrict__ w1v,
  const float* __restrict__ T, const float* __restrict__ qd, const float* __restrict__ validf,
  float* __restrict__ out)
{
  const int bi = blockIdx.x;
  const int b = bi / NN, i = bi - b*NN;
  const int tid = threadIdx.x;
  const int lane = tid & 63, wid = tid >> 6;

  __shared__ float qd_sh[28];
  __shared__ float w1_sh[320];                 // k(160) then v(160), pre-scaled
  __shared__ int   s_node[MAXM];
  __shared__ float s_cut[MAXM], s_dist[MAXM];
  __shared__ float s_shx[MAXM], s_shy[MAXM], s_shz[MAXM];
  __shared__ float emb_sh[MAXM*10];
  __shared__ float Hk_sh[MAXM*16];
  __shared__ float Hv_sh[MAXM*16];
  __shared__ float le_sh[MAXM];
  __shared__ float att_sh[MAXM];
  __shared__ int   cnt_sh;
  __shared__ float red_sh[4];
  __shared__ float opart[4][28];

  if (tid < 28) qd_sh[tid] = qd[bi*28 + tid];
  if (tid < 160) {                             // covers all 320 entries
    w1_sh[tid]       = w1k[tid] * RS10;
    w1_sh[160 + tid] = w1v[tid] * RS10;
  }
  if (tid == 0) cnt_sh = 0;
  const float pix = pos[bi*3+0], piy = pos[bi*3+1], piz = pos[bi*3+2];
  const float vali = validf[bi];
  __syncthreads();

  // Phase 1: mask + compaction
  if (tid < NN) {
    const int nj = b*NN + tid;
    const float dx = pos[nj*3+0]-pix, dy = pos[nj*3+1]-piy, dz = pos[nj*3+2]-piz;
    const float dist = sqrtf(fmaf(dx,dx,fmaf(dy,dy,dz*dz)) + 1e-12f);
    if (tid != i && dist < 1.5f && vali != 0.f && validf[nj] != 0.f) {
      const float cut = expf(-1.f / (10.f * (1.f - dist * (1.f/1.5f))));
      if (cut > 0.f) {
        const int s = atomicAdd(&cnt_sh, 1);
        const float sc = SQRT3 / dist;
        s_node[s] = nj; s_cut[s] = cut; s_dist[s] = dist;
        s_shx[s] = dx*sc; s_shy[s] = dy*sc; s_shz[s] = dz*sc;
      }
    }
  }
  __syncthreads();
  const int M = cnt_sh;
  const int MK = M * 16;

  // Phase 2a: radial basis per (pair, k)
  for (int idx = tid; idx < M*10; idx += 256) {
    const int pr = idx / 10, k = idx - pr*10;
    const float dd = (s_dist[pr] - (float)(k+1)*(1.5f/11.f)) * (11.f/1.5f);
    float e = 0.f;
    if (dd > -1.f && dd < 1.f) e = CEMB * expf(-1.f/(1.f+dd) - 1.f/(1.f-dd));
    emb_sh[idx] = e;
  }
  __syncthreads();

  // Phase 2b: FC hidden per (pair, fc, h)
  for (int idx = tid; idx < M*32; idx += 256) {
    const int pr = idx >> 5, t = idx & 31, h = t & 15;
    const float* w = w1_sh + (t >> 4)*160;
    const float* e = emb_sh + pr*10;
    float s = 0.f;
    #pragma unroll
    for (int q = 0; q < 10; ++q) s = fmaf(e[q], w[q*16 + h], s);
    const float hh = GAIN4 * s / (1.f + expf(-s));
    float* dst = (t < 16) ? Hk_sh : Hv_sh;
    dst[pr*16 + h] = hh;
  }
  __syncthreads();

  // Phase 2c: k-pass -> per-pair raw score in le_sh
  for (int idx = tid; idx < MK; idx += 256) {
    const int pr = idx >> 4, h = idx & 15;
    const int node = s_node[pr];
    const float sx = s_shx[pr], sy = s_shy[pr], sz = s_shz[pr];
    const float a = Hk_sh[idx];
    const float4* b4 = (const float4*)(T + (size_t)node*TSTRIDE);
    float cc[80];
    float4* c4 = (float4*)cc;
    #pragma unroll
    for (int q = 0; q < 20; ++q) c4[q] = b4[q*16 + h];
    float s = 0.f;
    #pragma unroll
    for (int o = 0; o < 16; ++o) {
      const float t4 = fmaf(cc[32+3*o], sx, fmaf(cc[33+3*o], sy, cc[34+3*o]*sz));
      s = fmaf(qd_sh[o], cc[o] + t4, s);
    }
    #pragma unroll
    for (int o = 0; o < 4; ++o) {
      const float qvs = fmaf(qd_sh[16+3*o], sx, fmaf(qd_sh[17+3*o], sy, qd_sh[18+3*o]*sz));
      s = fmaf(qvs, cc[16+o], s);
      s = fmaf(qd_sh[16+3*o], cc[20+3*o+0], s);
      s = fmaf(qd_sh[17+3*o], cc[20+3*o+1], s);
      s = fmaf(qd_sh[18+3*o], cc[20+3*o+2], s);
    }
    s *= a;
    #pragma unroll
    for (int d = 1; d < 16; d <<= 1) s += __shfl_xor(s, d);   // MK multiple of 16 -> uniform per 16-group
    if ((tid & 15) == 0) le_sh[pr] = s;
  }
  __syncthreads();

  // z + att per pair
  float les = 0.f;
  if (tid < M) les = s_cut[tid] * le_sh[tid];
  float z = les;
  #pragma unroll
  for (int d = 1; d < 64; d <<= 1) z += __shfl_xor(z, d);
  if (lane == 0) red_sh[wid] = z;
  __syncthreads();
  z = red_sh[0] + red_sh[1] + red_sh[2] + red_sh[3];
  if (z == 0.f) z = 1.f;
  if (tid < M) {
    const float alpha = les / z;
    att_sh[tid] = alpha > 0.f ? sqrtf(alpha) : 0.f;
  }
  __syncthreads();

  // Phase 3: v-pass with att folded in
  float acc[28];
  #pragma unroll
  for (int c = 0; c < 28; ++c) acc[c] = 0.f;
  for (int idx = tid; idx < MK; idx += 256) {
    const int pr = idx >> 4, h = idx & 15;
    const int node = s_node[pr];
    const float sx = s_shx[pr], sy = s_shy[pr], sz = s_shz[pr];
    const float a = Hv_sh[idx] * att_sh[pr];
    const float4* b4 = (const float4*)(T + (size_t)node*TSTRIDE + 1280);
    float cc[80];
    float4* c4 = (float4*)cc;
    #pragma unroll
    for (int q = 0; q < 20; ++q) c4[q] = b4[q*16 + h];
    #pragma unroll
    for (int o = 0; o < 16; ++o) {
      const float t4 = fmaf(cc[32+3*o], sx, fmaf(cc[33+3*o], sy, cc[34+3*o]*sz));
      acc[o] = fmaf(a, cc[o] + t4, acc[o]);
    }
    const float ax = a*sx, ay = a*sy, az = a*sz;
    #pragma unroll
    for (int o = 0; o < 4; ++o) {
      const float t2 = cc[16+o];
      acc[16+3*o+0] = fmaf(ax, t2, fmaf(a, cc[20+3*o+0], acc[16+3*o+0]));
      acc[16+3*o+1] = fmaf(ay, t2, fmaf(a, cc[20+3*o+1], acc[16+3*o+1]));
      acc[16+3*o+2] = fmaf(az, t2, fmaf(a, cc[20+3*o+2], acc[16+3*o+2]));
    }
  }

  // block-wide 28-element reduction
  #pragma unroll
  for (int c = 0; c < 28; ++c) {
    float w = acc[c];
    #pragma unroll
    for (int d = 1; d < 64; d <<= 1) w += __shfl_xor(w, d);
    if (lane == 0) opart[wid][c] = w;
  }
  __syncthreads();
  if (tid < 28) out[bi*28 + tid] = opart[0][tid] + opart[1][tid] + opart[2][tid] + opart[3][tid];
}

extern "C" void kernel_launch(void* const* d_in, const int* in_sizes, int n_in,
                              void* d_out, int out_size, void* d_ws, size_t ws_size,
                              hipStream_t stream) {
  const float* f      = (const float*)d_in[0];
  const float* pos    = (const float*)d_in[1];
  const float* wq_s   = (const float*)d_in[2];
  const float* wq_v   = (const float*)d_in[3];
  const float* fck_w1 = (const float*)d_in[4];
  const float* fck_w2 = (const float*)d_in[5];
  const float* fcv_w1 = (const float*)d_in[6];
  const float* fcv_w2 = (const float*)d_in[7];
  const float* dot_ws = (const float*)d_in[8];
  const float* dot_wv = (const float*)d_in[9];
  float* outp = (float*)d_out;

  const int BN = in_sizes[0] / 28;   // 768 nodes total (B*N)

  float* T   = (float*)d_ws;                      // BN * 2560
  float* qdp = T + (size_t)BN * TSTRIDE;          // BN * 28
  float* vf  = qdp + (size_t)BN * 28;             // BN

  const int NG = (BN + GN - 1) / GN;              // 48 node-groups
  precomp_T<<<NG * 32, 256, 0, stream>>>(f, wq_s, wq_v, fck_w2, fcv_w2, dot_ws, dot_wv, T, qdp, vf);
  se3_main<<<BN, 256, 0, stream>>>(pos, fck_w1, fcv_w1, T, qdp, vf, outp);
}